// Round 3
// baseline (480.352 us; speedup 1.0000x reference)
//
#include <hip/hip_runtime.h>
#include <hip/hip_bf16.h>

#define BB 4
#define SS 4096
#define DD 512
#define HH 512
#define TILE 128
#define NT 32

typedef __attribute__((ext_vector_type(8))) short bf16x8;

static __device__ __forceinline__ float bf2f(short s) {
    unsigned int u = ((unsigned int)(unsigned short)s) << 16;
    float f;
    __builtin_memcpy(&f, &u, 4);
    return f;
}

// ---------------------------------------------------------------------------
// q[b,h] = query[b,:]·Wq[:,h] + bq[h];  cq[b] = q[b,:]·bk
__global__ void k_qproj(const float* __restrict__ query, const float* __restrict__ Wq,
                        const float* __restrict__ bq, const float* __restrict__ bk,
                        float* __restrict__ qv, float* __restrict__ cq) {
    int b = blockIdx.x, tid = threadIdx.x;  // 256 threads
    __shared__ float qs[DD];
    __shared__ float red[256];
    for (int d = tid; d < DD; d += 256) qs[d] = query[b * DD + d];
    __syncthreads();
    int h0 = tid, h1 = tid + 256;
    float a0 = 0.f, a1 = 0.f;
    for (int d = 0; d < DD; ++d) {
        float qd = qs[d];
        a0 += qd * Wq[(size_t)d * HH + h0];
        a1 += qd * Wq[(size_t)d * HH + h1];
    }
    a0 += bq[h0]; a1 += bq[h1];
    qv[b * HH + h0] = a0; qv[b * HH + h1] = a1;
    red[tid] = a0 * bk[h0] + a1 * bk[h1];
    __syncthreads();
    for (int off = 128; off > 0; off >>= 1) {
        if (tid < off) red[tid] += red[tid + off];
        __syncthreads();
    }
    if (tid == 0) cq[b] = red[0];
}

// ---------------------------------------------------------------------------
// w[b,d] = sum_h Wk[d,h] * q[b,h]   (one wave per output)
__global__ void k_w(const float* __restrict__ Wk, const float* __restrict__ qv,
                    float* __restrict__ wout) {
    int bid = blockIdx.x;            // 512 blocks
    int b = bid >> 7, dg = bid & 127;
    int tid = threadIdx.x, wid = tid >> 6, lane = tid & 63;
    __shared__ float qs[HH];
    for (int h = tid; h < HH; h += 256) qs[h] = qv[b * HH + h];
    __syncthreads();
    int d = dg * 4 + wid;
    const float4* row = reinterpret_cast<const float4*>(Wk + (size_t)d * HH);
    float4 r0 = row[lane * 2], r1 = row[lane * 2 + 1];
    int h = lane * 8;
    float acc = r0.x * qs[h] + r0.y * qs[h + 1] + r0.z * qs[h + 2] + r0.w * qs[h + 3]
              + r1.x * qs[h + 4] + r1.y * qs[h + 5] + r1.z * qs[h + 6] + r1.w * qs[h + 7];
    for (int off = 32; off > 0; off >>= 1) acc += __shfl_down(acc, off);
    if (lane == 0) wout[b * DD + d] = acc;
}

// ---------------------------------------------------------------------------
// scores[b,s] = keys[b,s,:]·w[b,:] + cq[b]   (one wave per row)
__global__ void k_scores(const float* __restrict__ keys, const float* __restrict__ wv,
                         const float* __restrict__ cq, float* __restrict__ scores) {
    int bid = blockIdx.x;            // 4096 blocks
    int b = bid >> 10, sg = bid & 1023;
    int tid = threadIdx.x, wid = tid >> 6, lane = tid & 63;
    __shared__ float ws[DD];
    for (int d = tid; d < DD; d += 256) ws[d] = wv[b * DD + d];
    __syncthreads();
    int s = sg * 4 + wid;
    const float4* row = reinterpret_cast<const float4*>(keys + ((size_t)b * SS + s) * DD);
    float4 r0 = row[lane * 2], r1 = row[lane * 2 + 1];
    int h = lane * 8;
    float acc = r0.x * ws[h] + r0.y * ws[h + 1] + r0.z * ws[h + 2] + r0.w * ws[h + 3]
              + r1.x * ws[h + 4] + r1.y * ws[h + 5] + r1.z * ws[h + 6] + r1.w * ws[h + 7];
    for (int off = 32; off > 0; off >>= 1) acc += __shfl_down(acc, off);
    if (lane == 0) scores[b * SS + s] = acc + cq[b];
}

// ---------------------------------------------------------------------------
// p[s] = exp(scores[s]/sqrt(H) - M);  inv_cum[r] = 1 / inclusive_prefix(p)
__global__ __launch_bounds__(1024) void k_softmax(const float* __restrict__ scores,
                                                  float* __restrict__ p,
                                                  float* __restrict__ inv_cum) {
    int b = blockIdx.x, tid = threadIdx.x;   // 1024 threads, 4 elems each
    __shared__ float part[1024];
    const float inv_scale = 0.04419417382415922f;  // 1/sqrt(512)
    float loc[4];
    float mx = -1e30f;
    for (int j = 0; j < 4; ++j) {
        float x = scores[b * SS + tid * 4 + j] * inv_scale;
        loc[j] = x;
        mx = fmaxf(mx, x);
    }
    part[tid] = mx;
    __syncthreads();
    for (int off = 512; off > 0; off >>= 1) {
        if (tid < off) part[tid] = fmaxf(part[tid], part[tid + off]);
        __syncthreads();
    }
    float M = part[0];
    __syncthreads();
    float own = 0.f;
    for (int j = 0; j < 4; ++j) {
        loc[j] = expf(loc[j] - M);
        own += loc[j];
    }
    part[tid] = own;
    __syncthreads();
    // Hillis-Steele inclusive scan over 1024 partials
    for (int off = 1; off < 1024; off <<= 1) {
        float v = (tid >= off) ? part[tid - off] : 0.f;
        __syncthreads();
        part[tid] += v;
        __syncthreads();
    }
    float run = part[tid] - own;  // exclusive prefix
    for (int j = 0; j < 4; ++j) {
        run += loc[j];
        int s = tid * 4 + j;
        p[b * SS + s] = loc[j];
        inv_cum[b * SS + s] = 1.f / run;
    }
}

// ---------------------------------------------------------------------------
// attn[b,r,s] = (s<=r) ? p[b,s]*inv_cum[b,r] : 0   (fp32, 268 MB of stores)
__global__ void k_attn(const float* __restrict__ p, const float* __restrict__ inv_cum,
                       float* __restrict__ attn) {
    int r = blockIdx.x, b = blockIdx.y, tid = threadIdx.x;
    float ic = inv_cum[b * SS + r];
    const float* pb = p + b * SS;
    size_t base = ((size_t)b * SS + r) * SS;
    int s0 = tid * 16;
#pragma unroll
    for (int g = 0; g < 4; ++g) {
        int s = s0 + g * 4;
        float4 o;
        o.x = (s + 0 <= r) ? pb[s + 0] * ic : 0.f;
        o.y = (s + 1 <= r) ? pb[s + 1] * ic : 0.f;
        o.z = (s + 2 <= r) ? pb[s + 2] * ic : 0.f;
        o.w = (s + 3 <= r) ? pb[s + 3] * ic : 0.f;
        *reinterpret_cast<float4*>(&attn[base + s]) = o;
    }
}

// ---------------------------------------------------------------------------
// Pass A of the PV scan: per-tile sums T[b,t,d] = sum_{s in tile} p[s]*values[s,d]
__global__ void k_tile(const float* __restrict__ values, const float* __restrict__ p,
                       float* __restrict__ T) {
    int chunk = blockIdx.x, t = blockIdx.y, b = blockIdx.z, tid = threadIdx.x;
    __shared__ float ps[TILE];
    if (tid < TILE) ps[tid] = p[b * SS + t * TILE + tid];
    __syncthreads();
    int d = chunk * 256 + tid;
    const float* vp = values + ((size_t)b * SS + (size_t)t * TILE) * DD + d;
    float acc = 0.f;
    for (int i = 0; i < TILE; ++i) acc += ps[i] * vp[(size_t)i * DD];
    T[((size_t)b * NT + t) * DD + d] = acc;
}

// Pass C: within-tile inclusive scan + scale by inv_cum -> Cmat (bf16)
__global__ void k_scan(const float* __restrict__ values, const float* __restrict__ p,
                       const float* __restrict__ inv_cum, const float* __restrict__ T,
                       __hip_bfloat16* __restrict__ Cmat) {
    int chunk = blockIdx.x, t = blockIdx.y, b = blockIdx.z, tid = threadIdx.x;
    __shared__ float ps[TILE];
    __shared__ float ics[TILE];
    if (tid < TILE) ps[tid] = p[b * SS + t * TILE + tid];
    else { int i = tid - TILE; ics[i] = inv_cum[b * SS + t * TILE + i]; }
    __syncthreads();
    int d = chunk * 256 + tid;
    float acc = 0.f;
    for (int tp = 0; tp < t; ++tp) acc += T[((size_t)b * NT + tp) * DD + d];
    const float* vp = values + ((size_t)b * SS + (size_t)t * TILE) * DD + d;
    __hip_bfloat16* cp = Cmat + ((size_t)b * SS + (size_t)t * TILE) * DD + d;
    for (int i = 0; i < TILE; ++i) {
        acc += ps[i] * vp[(size_t)i * DD];
        cp[(size_t)i * DD] = __float2bfloat16(acc * ics[i]);
    }
}

// ---------------------------------------------------------------------------
// Wvo[k,n] = sum_h Wv[k,h]*Wo[h,n]  (512x512, fp32 tiled, fp32 output k-major)
__global__ void k_wvo(const float* __restrict__ Wv, const float* __restrict__ Wo,
                      float* __restrict__ Wvo) {
    __shared__ float lo[64][65];  // lo[h][n]
    __shared__ float lv[64][65];  // lv[k][h]
    int n0 = blockIdx.x * 64, k0 = blockIdx.y * 64, tid = threadIdx.x;
    int tn = (tid & 15) * 4, tk = (tid >> 4) * 4;
    float acc[4][4] = {};
    for (int h0 = 0; h0 < HH; h0 += 64) {
        for (int i = tid; i < 64 * 64; i += 256) {
            int rr = i >> 6, cc = i & 63;
            lo[rr][cc] = Wo[(size_t)(h0 + rr) * DD + n0 + cc];
            lv[rr][cc] = Wv[(size_t)(k0 + rr) * HH + h0 + cc];
        }
        __syncthreads();
        for (int h = 0; h < 64; ++h)
#pragma unroll
            for (int a = 0; a < 4; ++a) {
                float vv = lv[tk + a][h];
#pragma unroll
                for (int c = 0; c < 4; ++c) acc[a][c] += vv * lo[h][tn + c];
            }
        __syncthreads();
    }
    for (int a = 0; a < 4; ++a)
        for (int c = 0; c < 4; ++c)
            Wvo[(size_t)(k0 + tk + a) * DD + n0 + tn + c] = acc[a][c];
}

// bfinal[n] = bv·Wo[:,n] + bo[n]
__global__ void k_bfinal(const float* __restrict__ bv, const float* __restrict__ Wo,
                         const float* __restrict__ bo, float* __restrict__ bfinal) {
    int n = blockIdx.x * 256 + threadIdx.x;
    float acc = bo[n];
    for (int h = 0; h < HH; ++h) acc += bv[h] * Wo[(size_t)h * DD + n];
    bfinal[n] = acc;
}

// ---------------------------------------------------------------------------
// out[m,n] = Cmat[m,:] @ Wvo[:,n] + bfinal[n]   (fp32 output)
// Conservative fp32 VALU GEMM (64x64 tile, 4x4/thread) — MFMA next round.
__global__ __launch_bounds__(256) void k_out(const __hip_bfloat16* __restrict__ A,
                                             const float* __restrict__ Bw,
                                             const float* __restrict__ bfinal,
                                             float* __restrict__ Out) {
    __shared__ float As[64][33];
    __shared__ float Bs[32][66];
    int m0 = blockIdx.x * 64, n0 = blockIdx.y * 64;
    int tid = threadIdx.x;
    int tx = tid & 15, ty = tid >> 4;
    float acc[4][4] = {};
    for (int k0 = 0; k0 < 512; k0 += 32) {
        // stage A: 64x32 bf16 -> f32 (8 contiguous per thread)
        {
            int row = tid >> 2, cg = (tid & 3) * 8;
            const short* ap = reinterpret_cast<const short*>(A) + (size_t)(m0 + row) * 512 + k0 + cg;
            bf16x8 v = *reinterpret_cast<const bf16x8*>(ap);
#pragma unroll
            for (int j = 0; j < 8; ++j) As[row][cg + j] = bf2f(v[j]);
        }
        // stage B: 32x64 f32 (8 contiguous per thread)
        {
            int row = tid >> 3, cg = (tid & 7) * 8;
            const float4* bp = reinterpret_cast<const float4*>(Bw + (size_t)(k0 + row) * 512 + n0 + cg);
            float4 b0 = bp[0], b1 = bp[1];
            Bs[row][cg + 0] = b0.x; Bs[row][cg + 1] = b0.y;
            Bs[row][cg + 2] = b0.z; Bs[row][cg + 3] = b0.w;
            Bs[row][cg + 4] = b1.x; Bs[row][cg + 5] = b1.y;
            Bs[row][cg + 6] = b1.z; Bs[row][cg + 7] = b1.w;
        }
        __syncthreads();
#pragma unroll 4
        for (int kk = 0; kk < 32; ++kk) {
            float a[4], bb[4];
#pragma unroll
            for (int i = 0; i < 4; ++i) a[i] = As[ty * 4 + i][kk];
#pragma unroll
            for (int j = 0; j < 4; ++j) bb[j] = Bs[kk][tx * 4 + j];
#pragma unroll
            for (int i = 0; i < 4; ++i)
#pragma unroll
                for (int j = 0; j < 4; ++j) acc[i][j] += a[i] * bb[j];
        }
        __syncthreads();
    }
    for (int i = 0; i < 4; ++i) {
        int row = m0 + ty * 4 + i;
#pragma unroll
        for (int j = 0; j < 4; ++j) {
            int col = n0 + tx * 4 + j;
            Out[(size_t)row * 512 + col] = acc[i][j] + bfinal[col];
        }
    }
}

// ---------------------------------------------------------------------------
extern "C" void kernel_launch(void* const* d_in, const int* in_sizes, int n_in,
                              void* d_out, int out_size, void* d_ws, size_t ws_size,
                              hipStream_t stream) {
    const float* query  = (const float*)d_in[0];
    const float* keys   = (const float*)d_in[1];
    const float* values = (const float*)d_in[2];
    const float* Wq = (const float*)d_in[3];
    const float* bq = (const float*)d_in[4];
    const float* Wk = (const float*)d_in[5];
    const float* bk = (const float*)d_in[6];
    const float* Wv = (const float*)d_in[7];
    const float* bv = (const float*)d_in[8];
    const float* Wo = (const float*)d_in[9];
    const float* bo = (const float*)d_in[10];

    float* out  = (float*)d_out;                       // (B,S,D) fp32
    float* attn = out + (size_t)BB * SS * DD;          // (B,S,S) fp32, 268 MB
    __hip_bfloat16* Cmat = (__hip_bfloat16*)attn;      // 16.8 MB scratch inside attn region

    // d_ws usage: ~1.5 MB total
    char* ws = (char*)d_ws;
    float* Wvo  = (float*)(ws);                 // 1,048,576 B
    float* T    = (float*)(ws + 1048576);       //   262,144 B
    float* p    = (float*)(ws + 1310720);       //    65,536 B
    float* icum = (float*)(ws + 1376256);       //    65,536 B
    float* scr  = (float*)(ws + 1441792);       //    65,536 B
    float* qv   = (float*)(ws + 1507328);       //     8,192 B
    float* wv   = (float*)(ws + 1515520);       //     8,192 B
    float* cq   = (float*)(ws + 1523712);       //       256 B
    float* bfin = (float*)(ws + 1523968);       //     2,048 B

    k_wvo   <<<dim3(8, 8),       256, 0, stream>>>(Wv, Wo, Wvo);
    k_bfinal<<<2,                256, 0, stream>>>(bv, Wo, bo, bfin);
    k_qproj <<<BB,               256, 0, stream>>>(query, Wq, bq, bk, qv, cq);
    k_w     <<<512,              256, 0, stream>>>(Wk, qv, wv);
    k_scores<<<4096,             256, 0, stream>>>(keys, wv, cq, scr);
    k_softmax<<<BB,             1024, 0, stream>>>(scr, p, icum);
    k_tile  <<<dim3(2, NT, BB),  256, 0, stream>>>(values, p, T);
    k_scan  <<<dim3(2, NT, BB),  256, 0, stream>>>(values, p, icum, T, Cmat);
    k_out   <<<dim3(256, 8),     256, 0, stream>>>(Cmat, Wvo, bfin, out);
    // k_attn LAST: it overwrites the attn region that held Cmat scratch
    k_attn  <<<dim3(SS, BB),     256, 0, stream>>>(p, icum, attn);
}

// Round 4
// 372.891 us; speedup vs baseline: 1.2882x; 1.2882x over previous
//
#include <hip/hip_runtime.h>
#include <hip/hip_bf16.h>

#define BB 4
#define SS 4096
#define DD 512
#define HH 512
#define TILE 128
#define NT 32

typedef __attribute__((ext_vector_type(8))) short bf16x8;
typedef __attribute__((ext_vector_type(4))) float f32x4;

// ---------------------------------------------------------------------------
// q[b,h] = query[b,:]·Wq[:,h] + bq[h];  cq[b] = q[b,:]·bk
__global__ void k_qproj(const float* __restrict__ query, const float* __restrict__ Wq,
                        const float* __restrict__ bq, const float* __restrict__ bk,
                        float* __restrict__ qv, float* __restrict__ cq) {
    int b = blockIdx.x, tid = threadIdx.x;  // 256 threads
    __shared__ float qs[DD];
    __shared__ float red[256];
    for (int d = tid; d < DD; d += 256) qs[d] = query[b * DD + d];
    __syncthreads();
    int h0 = tid, h1 = tid + 256;
    float a0 = 0.f, a1 = 0.f;
    for (int d = 0; d < DD; ++d) {
        float qd = qs[d];
        a0 += qd * Wq[(size_t)d * HH + h0];
        a1 += qd * Wq[(size_t)d * HH + h1];
    }
    a0 += bq[h0]; a1 += bq[h1];
    qv[b * HH + h0] = a0; qv[b * HH + h1] = a1;
    red[tid] = a0 * bk[h0] + a1 * bk[h1];
    __syncthreads();
    for (int off = 128; off > 0; off >>= 1) {
        if (tid < off) red[tid] += red[tid + off];
        __syncthreads();
    }
    if (tid == 0) cq[b] = red[0];
}

// ---------------------------------------------------------------------------
// w[b,d] = sum_h Wk[d,h] * q[b,h]   (one wave per output)
__global__ void k_w(const float* __restrict__ Wk, const float* __restrict__ qv,
                    float* __restrict__ wout) {
    int bid = blockIdx.x;            // 512 blocks
    int b = bid >> 7, dg = bid & 127;
    int tid = threadIdx.x, wid = tid >> 6, lane = tid & 63;
    __shared__ float qs[HH];
    for (int h = tid; h < HH; h += 256) qs[h] = qv[b * HH + h];
    __syncthreads();
    int d = dg * 4 + wid;
    const float4* row = reinterpret_cast<const float4*>(Wk + (size_t)d * HH);
    float4 r0 = row[lane * 2], r1 = row[lane * 2 + 1];
    int h = lane * 8;
    float acc = r0.x * qs[h] + r0.y * qs[h + 1] + r0.z * qs[h + 2] + r0.w * qs[h + 3]
              + r1.x * qs[h + 4] + r1.y * qs[h + 5] + r1.z * qs[h + 6] + r1.w * qs[h + 7];
    for (int off = 32; off > 0; off >>= 1) acc += __shfl_down(acc, off);
    if (lane == 0) wout[b * DD + d] = acc;
}

// ---------------------------------------------------------------------------
// scores[b,s] = keys[b,s,:]·w[b,:] + cq[b]   (one wave per row)
__global__ void k_scores(const float* __restrict__ keys, const float* __restrict__ wv,
                         const float* __restrict__ cq, float* __restrict__ scores) {
    int bid = blockIdx.x;            // 4096 blocks
    int b = bid >> 10, sg = bid & 1023;
    int tid = threadIdx.x, wid = tid >> 6, lane = tid & 63;
    __shared__ float ws[DD];
    for (int d = tid; d < DD; d += 256) ws[d] = wv[b * DD + d];
    __syncthreads();
    int s = sg * 4 + wid;
    const float4* row = reinterpret_cast<const float4*>(keys + ((size_t)b * SS + s) * DD);
    float4 r0 = row[lane * 2], r1 = row[lane * 2 + 1];
    int h = lane * 8;
    float acc = r0.x * ws[h] + r0.y * ws[h + 1] + r0.z * ws[h + 2] + r0.w * ws[h + 3]
              + r1.x * ws[h + 4] + r1.y * ws[h + 5] + r1.z * ws[h + 6] + r1.w * ws[h + 7];
    for (int off = 32; off > 0; off >>= 1) acc += __shfl_down(acc, off);
    if (lane == 0) scores[b * SS + s] = acc + cq[b];
}

// ---------------------------------------------------------------------------
// p[s] = exp(scores[s]/sqrt(H) - M);  inv_cum[r] = 1 / inclusive_prefix(p)
__global__ __launch_bounds__(1024) void k_softmax(const float* __restrict__ scores,
                                                  float* __restrict__ p,
                                                  float* __restrict__ inv_cum) {
    int b = blockIdx.x, tid = threadIdx.x;   // 1024 threads, 4 elems each
    __shared__ float part[1024];
    const float inv_scale = 0.04419417382415922f;  // 1/sqrt(512)
    float loc[4];
    float mx = -1e30f;
    for (int j = 0; j < 4; ++j) {
        float x = scores[b * SS + tid * 4 + j] * inv_scale;
        loc[j] = x;
        mx = fmaxf(mx, x);
    }
    part[tid] = mx;
    __syncthreads();
    for (int off = 512; off > 0; off >>= 1) {
        if (tid < off) part[tid] = fmaxf(part[tid], part[tid + off]);
        __syncthreads();
    }
    float M = part[0];
    __syncthreads();
    float own = 0.f;
    for (int j = 0; j < 4; ++j) {
        loc[j] = expf(loc[j] - M);
        own += loc[j];
    }
    part[tid] = own;
    __syncthreads();
    // Hillis-Steele inclusive scan over 1024 partials
    for (int off = 1; off < 1024; off <<= 1) {
        float v = (tid >= off) ? part[tid - off] : 0.f;
        __syncthreads();
        part[tid] += v;
        __syncthreads();
    }
    float run = part[tid] - own;  // exclusive prefix
    for (int j = 0; j < 4; ++j) {
        run += loc[j];
        int s = tid * 4 + j;
        p[b * SS + s] = loc[j];
        inv_cum[b * SS + s] = 1.f / run;
    }
}

// ---------------------------------------------------------------------------
// attn[b,r,s] = (s<=r) ? p[b,s]*inv_cum[b,r] : 0   (fp32, 268 MB of stores)
__global__ void k_attn(const float* __restrict__ p, const float* __restrict__ inv_cum,
                       float* __restrict__ attn) {
    int r = blockIdx.x, b = blockIdx.y, tid = threadIdx.x;
    float ic = inv_cum[b * SS + r];
    const float* pb = p + b * SS;
    size_t base = ((size_t)b * SS + r) * SS;
    int s0 = tid * 16;
#pragma unroll
    for (int g = 0; g < 4; ++g) {
        int s = s0 + g * 4;
        float4 o;
        o.x = (s + 0 <= r) ? pb[s + 0] * ic : 0.f;
        o.y = (s + 1 <= r) ? pb[s + 1] * ic : 0.f;
        o.z = (s + 2 <= r) ? pb[s + 2] * ic : 0.f;
        o.w = (s + 3 <= r) ? pb[s + 3] * ic : 0.f;
        *reinterpret_cast<float4*>(&attn[base + s]) = o;
    }
}

// ---------------------------------------------------------------------------
// Pass A of the PV scan: per-tile sums T[b,t,d] = sum_{s in tile} p[s]*values[s,d]
__global__ void k_tile(const float* __restrict__ values, const float* __restrict__ p,
                       float* __restrict__ T) {
    int chunk = blockIdx.x, t = blockIdx.y, b = blockIdx.z, tid = threadIdx.x;
    __shared__ float ps[TILE];
    if (tid < TILE) ps[tid] = p[b * SS + t * TILE + tid];
    __syncthreads();
    int d = chunk * 256 + tid;
    const float* vp = values + ((size_t)b * SS + (size_t)t * TILE) * DD + d;
    float acc = 0.f;
    for (int i = 0; i < TILE; ++i) acc += ps[i] * vp[(size_t)i * DD];
    T[((size_t)b * NT + t) * DD + d] = acc;
}

// Pass C: within-tile inclusive scan + scale by inv_cum -> Cmat (bf16)
__global__ void k_scan(const float* __restrict__ values, const float* __restrict__ p,
                       const float* __restrict__ inv_cum, const float* __restrict__ T,
                       __hip_bfloat16* __restrict__ Cmat) {
    int chunk = blockIdx.x, t = blockIdx.y, b = blockIdx.z, tid = threadIdx.x;
    __shared__ float ps[TILE];
    __shared__ float ics[TILE];
    if (tid < TILE) ps[tid] = p[b * SS + t * TILE + tid];
    else { int i = tid - TILE; ics[i] = inv_cum[b * SS + t * TILE + i]; }
    __syncthreads();
    int d = chunk * 256 + tid;
    float acc = 0.f;
    for (int tp = 0; tp < t; ++tp) acc += T[((size_t)b * NT + tp) * DD + d];
    const float* vp = values + ((size_t)b * SS + (size_t)t * TILE) * DD + d;
    __hip_bfloat16* cp = Cmat + ((size_t)b * SS + (size_t)t * TILE) * DD + d;
    for (int i = 0; i < TILE; ++i) {
        acc += ps[i] * vp[(size_t)i * DD];
        cp[(size_t)i * DD] = __float2bfloat16(acc * ics[i]);
    }
}

// ---------------------------------------------------------------------------
// WvoT[n,k] = sum_h Wv[k,h]*Wo[h,n]  (512x512 fp32 compute, bf16 B^T output)
__global__ void k_wvo(const float* __restrict__ Wv, const float* __restrict__ Wo,
                      __hip_bfloat16* __restrict__ WvoT) {
    __shared__ float lo[64][65];  // lo[h][n]
    __shared__ float lv[64][65];  // lv[k][h]
    int n0 = blockIdx.x * 64, k0 = blockIdx.y * 64, tid = threadIdx.x;
    int tn = (tid & 15) * 4, tk = (tid >> 4) * 4;
    float acc[4][4] = {};
    for (int h0 = 0; h0 < HH; h0 += 64) {
        for (int i = tid; i < 64 * 64; i += 256) {
            int rr = i >> 6, cc = i & 63;
            lo[rr][cc] = Wo[(size_t)(h0 + rr) * DD + n0 + cc];
            lv[rr][cc] = Wv[(size_t)(k0 + rr) * HH + h0 + cc];
        }
        __syncthreads();
        for (int h = 0; h < 64; ++h)
#pragma unroll
            for (int a = 0; a < 4; ++a) {
                float vv = lv[tk + a][h];
#pragma unroll
                for (int c = 0; c < 4; ++c) acc[a][c] += vv * lo[h][tn + c];
            }
        __syncthreads();
    }
    for (int a = 0; a < 4; ++a)
        for (int c = 0; c < 4; ++c)
            WvoT[(size_t)(n0 + tn + c) * DD + k0 + tk + a] = __float2bfloat16(acc[a][c]);
}

// bfinal[n] = bv·Wo[:,n] + bo[n]
__global__ void k_bfinal(const float* __restrict__ bv, const float* __restrict__ Wo,
                         const float* __restrict__ bo, float* __restrict__ bfinal) {
    int n = blockIdx.x * 256 + threadIdx.x;
    float acc = bo[n];
    for (int h = 0; h < HH; ++h) acc += bv[h] * Wo[(size_t)h * DD + n];
    bfinal[n] = acc;
}

// ---------------------------------------------------------------------------
// out[m,n] = Cmat[m,:] @ WvoT[n,:]^T + bfinal[n]  (bf16 MFMA, fp32 output)
// A frag: row=lane&15, k=(lane>>4)*8..+7 ; B^T frag same; C/D: col=lane&15,
// row=(lane>>4)*4+reg  [verified layout, learn_hip m89/m91]
__global__ __launch_bounds__(256) void k_out(const __hip_bfloat16* __restrict__ A,
                                             const __hip_bfloat16* __restrict__ Bt,
                                             const float* __restrict__ bfinal,
                                             float* __restrict__ Out) {
    int m0 = blockIdx.x * 64;
    int n0 = blockIdx.y * 256 + (threadIdx.x >> 6) * 64;
    int lane = threadIdx.x & 63;
    int lrow = lane & 15, lk = (lane >> 4) * 8;
    f32x4 acc[4][4] = {};
    const short* Ap = reinterpret_cast<const short*>(A);
    const short* Bp = reinterpret_cast<const short*>(Bt);
    for (int kk = 0; kk < 512; kk += 32) {
        bf16x8 af[4], bfr[4];
#pragma unroll
        for (int i = 0; i < 4; ++i)
            af[i] = *reinterpret_cast<const bf16x8*>(Ap + (size_t)(m0 + i * 16 + lrow) * 512 + kk + lk);
#pragma unroll
        for (int i = 0; i < 4; ++i)
            bfr[i] = *reinterpret_cast<const bf16x8*>(Bp + (size_t)(n0 + i * 16 + lrow) * 512 + kk + lk);
#pragma unroll
        for (int i = 0; i < 4; ++i)
#pragma unroll
            for (int j = 0; j < 4; ++j)
                acc[i][j] = __builtin_amdgcn_mfma_f32_16x16x32_bf16(af[i], bfr[j], acc[i][j], 0, 0, 0);
    }
    int rbase = (lane >> 4) * 4;
    for (int i = 0; i < 4; ++i)
        for (int j = 0; j < 4; ++j) {
            int col = n0 + j * 16 + lrow;
            float bb = bfinal[col];
#pragma unroll
            for (int r = 0; r < 4; ++r) {
                int row = m0 + i * 16 + rbase + r;
                Out[(size_t)row * 512 + col] = acc[i][j][r] + bb;
            }
        }
}

// ---------------------------------------------------------------------------
extern "C" void kernel_launch(void* const* d_in, const int* in_sizes, int n_in,
                              void* d_out, int out_size, void* d_ws, size_t ws_size,
                              hipStream_t stream) {
    const float* query  = (const float*)d_in[0];
    const float* keys   = (const float*)d_in[1];
    const float* values = (const float*)d_in[2];
    const float* Wq = (const float*)d_in[3];
    const float* bq = (const float*)d_in[4];
    const float* Wk = (const float*)d_in[5];
    const float* bk = (const float*)d_in[6];
    const float* Wv = (const float*)d_in[7];
    const float* bv = (const float*)d_in[8];
    const float* Wo = (const float*)d_in[9];
    const float* bo = (const float*)d_in[10];

    float* out  = (float*)d_out;                       // (B,S,D) fp32
    float* attn = out + (size_t)BB * SS * DD;          // (B,S,S) fp32, 268 MB
    __hip_bfloat16* Cmat = (__hip_bfloat16*)attn;      // 16.8 MB scratch inside attn region

    // d_ws usage: ~1.5 MB total
    char* ws = (char*)d_ws;
    __hip_bfloat16* WvoT = (__hip_bfloat16*)(ws);      //   524,288 B
    float* T    = (float*)(ws + 524288);               //   262,144 B
    float* p    = (float*)(ws + 786432);               //    65,536 B
    float* icum = (float*)(ws + 851968);               //    65,536 B
    float* scr  = (float*)(ws + 917504);               //    65,536 B
    float* qv   = (float*)(ws + 983040);               //     8,192 B
    float* wv   = (float*)(ws + 991232);               //     8,192 B
    float* cq   = (float*)(ws + 999424);               //       256 B
    float* bfin = (float*)(ws + 999680);               //     2,048 B

    k_wvo   <<<dim3(8, 8),       256, 0, stream>>>(Wv, Wo, WvoT);
    k_bfinal<<<2,                256, 0, stream>>>(bv, Wo, bo, bfin);
    k_qproj <<<BB,               256, 0, stream>>>(query, Wq, bq, bk, qv, cq);
    k_w     <<<512,              256, 0, stream>>>(Wk, qv, wv);
    k_scores<<<4096,             256, 0, stream>>>(keys, wv, cq, scr);
    k_softmax<<<BB,             1024, 0, stream>>>(scr, p, icum);
    k_tile  <<<dim3(2, NT, BB),  256, 0, stream>>>(values, p, T);
    k_scan  <<<dim3(2, NT, BB),  256, 0, stream>>>(values, p, icum, T, Cmat);
    k_out   <<<dim3(256, 2),     256, 0, stream>>>(Cmat, WvoT, bfin, out);
    // k_attn LAST: it overwrites the attn region that held Cmat scratch
    k_attn  <<<dim3(SS, BB),     256, 0, stream>>>(p, icum, attn);
}

// Round 5
// 321.204 us; speedup vs baseline: 1.4955x; 1.1609x over previous
//
#include <hip/hip_runtime.h>
#include <hip/hip_bf16.h>

#define BB 4
#define SS 4096
#define DD 512
#define HH 512
#define TILE 128
#define NT 32

typedef __attribute__((ext_vector_type(8))) short bf16x8;
typedef __attribute__((ext_vector_type(4))) float f32x4;

// ---------------------------------------------------------------------------
// q[b,h] = query[b,:]·Wq[:,h] + bq[h]   (grid: 8 h-groups x 4 b, 4 thr/output)
__global__ void k_qproj(const float* __restrict__ query, const float* __restrict__ Wq,
                        const float* __restrict__ bq, float* __restrict__ qv) {
    int hg = blockIdx.x, b = blockIdx.y, tid = threadIdx.x;
    int hl = tid & 63, qq = tid >> 6;
    int h = hg * 64 + hl;
    __shared__ float qs[DD];
    __shared__ float red[4][64];
    for (int d = tid; d < DD; d += 256) qs[d] = query[b * DD + d];
    __syncthreads();
    float a = 0.f;
    int d0 = qq * 128;
    for (int d = d0; d < d0 + 128; ++d)
        a += qs[d] * Wq[(size_t)d * HH + h];
    red[qq][hl] = a;
    __syncthreads();
    if (tid < 64)
        qv[b * HH + hg * 64 + tid] = red[0][tid] + red[1][tid] + red[2][tid] + red[3][tid]
                                   + bq[hg * 64 + tid];
}

// ---------------------------------------------------------------------------
// w[b,d] = sum_h Wk[d,h]*q[b,h];  block dg==0 also computes cq[b] = q[b]·bk
__global__ void k_w(const float* __restrict__ Wk, const float* __restrict__ qv,
                    const float* __restrict__ bk,
                    float* __restrict__ wout, float* __restrict__ cq) {
    int bid = blockIdx.x;            // 512 blocks
    int b = bid >> 7, dg = bid & 127;
    int tid = threadIdx.x, wid = tid >> 6, lane = tid & 63;
    __shared__ float qs[HH];
    __shared__ float red[256];
    for (int h = tid; h < HH; h += 256) qs[h] = qv[b * HH + h];
    __syncthreads();
    int d = dg * 4 + wid;
    const float4* row = reinterpret_cast<const float4*>(Wk + (size_t)d * HH);
    float4 r0 = row[lane * 2], r1 = row[lane * 2 + 1];
    int h = lane * 8;
    float acc = r0.x * qs[h] + r0.y * qs[h + 1] + r0.z * qs[h + 2] + r0.w * qs[h + 3]
              + r1.x * qs[h + 4] + r1.y * qs[h + 5] + r1.z * qs[h + 6] + r1.w * qs[h + 7];
    for (int off = 32; off > 0; off >>= 1) acc += __shfl_down(acc, off);
    if (lane == 0) wout[b * DD + d] = acc;
    if (dg == 0) {
        red[tid] = qs[tid] * bk[tid] + qs[tid + 256] * bk[tid + 256];
        __syncthreads();
        for (int off = 128; off > 0; off >>= 1) {
            if (tid < off) red[tid] += red[tid + off];
            __syncthreads();
        }
        if (tid == 0) cq[b] = red[0];
    }
}

// ---------------------------------------------------------------------------
// scores[b,s] = keys[b,s,:]·w[b,:] + cq[b]   (one wave per row)
__global__ void k_scores(const float* __restrict__ keys, const float* __restrict__ wv,
                         const float* __restrict__ cq, float* __restrict__ scores) {
    int bid = blockIdx.x;            // 4096 blocks
    int b = bid >> 10, sg = bid & 1023;
    int tid = threadIdx.x, wid = tid >> 6, lane = tid & 63;
    __shared__ float ws[DD];
    for (int d = tid; d < DD; d += 256) ws[d] = wv[b * DD + d];
    __syncthreads();
    int s = sg * 4 + wid;
    const float4* row = reinterpret_cast<const float4*>(keys + ((size_t)b * SS + s) * DD);
    float4 r0 = row[lane * 2], r1 = row[lane * 2 + 1];
    int h = lane * 8;
    float acc = r0.x * ws[h] + r0.y * ws[h + 1] + r0.z * ws[h + 2] + r0.w * ws[h + 3]
              + r1.x * ws[h + 4] + r1.y * ws[h + 5] + r1.z * ws[h + 6] + r1.w * ws[h + 7];
    for (int off = 32; off > 0; off >>= 1) acc += __shfl_down(acc, off);
    if (lane == 0) scores[b * SS + s] = acc + cq[b];
}

// ---------------------------------------------------------------------------
// p[s] = exp(scores[s]/sqrt(H) - M);  inv_cum[r] = 1/inclusive_prefix(p)
// Wave-shuffle max + scan: 2 barriers total (was ~30).
__global__ __launch_bounds__(1024) void k_softmax(const float* __restrict__ scores,
                                                  float* __restrict__ p,
                                                  float* __restrict__ inv_cum) {
    int b = blockIdx.x, tid = threadIdx.x;   // 1024 threads, 4 elems each
    int wid = tid >> 6, lane = tid & 63;
    __shared__ float wmax[16];
    __shared__ float wsum[16];
    const float inv_scale = 0.04419417382415922f;  // 1/sqrt(512)
    float4 sv = *reinterpret_cast<const float4*>(scores + (size_t)b * SS + tid * 4);
    float loc[4] = {sv.x * inv_scale, sv.y * inv_scale, sv.z * inv_scale, sv.w * inv_scale};
    float mx = fmaxf(fmaxf(loc[0], loc[1]), fmaxf(loc[2], loc[3]));
    for (int off = 32; off > 0; off >>= 1) mx = fmaxf(mx, __shfl_xor(mx, off));
    if (lane == 0) wmax[wid] = mx;
    __syncthreads();
    float M = wmax[0];
    for (int i = 1; i < 16; ++i) M = fmaxf(M, wmax[i]);
    float own = 0.f;
    for (int j = 0; j < 4; ++j) {
        loc[j] = expf(loc[j] - M);
        own += loc[j];
    }
    // wave inclusive scan of per-thread sums
    float incl = own;
    for (int off = 1; off < 64; off <<= 1) {
        float v = __shfl_up(incl, off);
        if (lane >= off) incl += v;
    }
    if (lane == 63) wsum[wid] = incl;
    __syncthreads();
    float woff = 0.f;
    for (int i = 0; i < wid; ++i) woff += wsum[i];
    float run = woff + incl - own;   // exclusive prefix for this thread
    float4 pv, iv;
    run += loc[0]; pv.x = loc[0]; iv.x = 1.f / run;
    run += loc[1]; pv.y = loc[1]; iv.y = 1.f / run;
    run += loc[2]; pv.z = loc[2]; iv.z = 1.f / run;
    run += loc[3]; pv.w = loc[3]; iv.w = 1.f / run;
    *reinterpret_cast<float4*>(p + (size_t)b * SS + tid * 4) = pv;
    *reinterpret_cast<float4*>(inv_cum + (size_t)b * SS + tid * 4) = iv;
}

// ---------------------------------------------------------------------------
// attn[b,r,s] = (s<=r) ? p[b,s]*inv_cum[b,r] : 0   (fp32, 268 MB of stores)
__global__ void k_attn(const float* __restrict__ p, const float* __restrict__ inv_cum,
                       float* __restrict__ attn) {
    int r = blockIdx.x, b = blockIdx.y, tid = threadIdx.x;
    float ic = inv_cum[b * SS + r];
    const float* pb = p + b * SS;
    size_t base = ((size_t)b * SS + r) * SS;
    int s0 = tid * 16;
#pragma unroll
    for (int g = 0; g < 4; ++g) {
        int s = s0 + g * 4;
        float4 o;
        o.x = (s + 0 <= r) ? pb[s + 0] * ic : 0.f;
        o.y = (s + 1 <= r) ? pb[s + 1] * ic : 0.f;
        o.z = (s + 2 <= r) ? pb[s + 2] * ic : 0.f;
        o.w = (s + 3 <= r) ? pb[s + 3] * ic : 0.f;
        *reinterpret_cast<float4*>(&attn[base + s]) = o;
    }
}

// ---------------------------------------------------------------------------
// Pass A of the PV scan: per-tile sums T[b,t,d] = sum_{s in tile} p[s]*values[s,d]
__global__ void k_tile(const float* __restrict__ values, const float* __restrict__ p,
                       float* __restrict__ T) {
    int chunk = blockIdx.x, t = blockIdx.y, b = blockIdx.z, tid = threadIdx.x;
    __shared__ float ps[TILE];
    if (tid < TILE) ps[tid] = p[b * SS + t * TILE + tid];
    __syncthreads();
    int d = chunk * 256 + tid;
    const float* vp = values + ((size_t)b * SS + (size_t)t * TILE) * DD + d;
    float acc = 0.f;
    for (int i = 0; i < TILE; ++i) acc += ps[i] * vp[(size_t)i * DD];
    T[((size_t)b * NT + t) * DD + d] = acc;
}

// Pass C: within-tile inclusive scan + scale by inv_cum -> Cmat (bf16)
__global__ void k_scan(const float* __restrict__ values, const float* __restrict__ p,
                       const float* __restrict__ inv_cum, const float* __restrict__ T,
                       __hip_bfloat16* __restrict__ Cmat) {
    int chunk = blockIdx.x, t = blockIdx.y, b = blockIdx.z, tid = threadIdx.x;
    __shared__ float ps[TILE];
    __shared__ float ics[TILE];
    if (tid < TILE) ps[tid] = p[b * SS + t * TILE + tid];
    else { int i = tid - TILE; ics[i] = inv_cum[b * SS + t * TILE + i]; }
    __syncthreads();
    int d = chunk * 256 + tid;
    float acc = 0.f;
    for (int tp = 0; tp < t; ++tp) acc += T[((size_t)b * NT + tp) * DD + d];
    const float* vp = values + ((size_t)b * SS + (size_t)t * TILE) * DD + d;
    __hip_bfloat16* cp = Cmat + ((size_t)b * SS + (size_t)t * TILE) * DD + d;
    for (int i = 0; i < TILE; ++i) {
        acc += ps[i] * vp[(size_t)i * DD];
        cp[(size_t)i * DD] = __float2bfloat16(acc * ics[i]);
    }
}

// ---------------------------------------------------------------------------
// WvoT[n,k] = sum_h Wv[k,h]*Wo[h,n] (bf16 B^T out); blocks with k0==0 also
// compute bfinal[n] = bv·Wo[:,n] + bo[n] from the already-staged lo tiles.
__global__ void k_wvo(const float* __restrict__ Wv, const float* __restrict__ Wo,
                      const float* __restrict__ bv, const float* __restrict__ bo,
                      __hip_bfloat16* __restrict__ WvoT, float* __restrict__ bfinal) {
    __shared__ float lo[64][65];  // lo[h][n]
    __shared__ float lv[64][65];  // lv[k][h]
    int n0 = blockIdx.x * 64, k0 = blockIdx.y * 64, tid = threadIdx.x;
    int tn = (tid & 15) * 4, tk = (tid >> 4) * 4;
    int bn = tid & 63, bq_ = tid >> 6;
    float acc[4][4] = {};
    float bfacc = 0.f;
    for (int h0 = 0; h0 < HH; h0 += 64) {
        for (int i = tid; i < 64 * 64; i += 256) {
            int rr = i >> 6, cc = i & 63;
            lo[rr][cc] = Wo[(size_t)(h0 + rr) * DD + n0 + cc];
            lv[rr][cc] = Wv[(size_t)(k0 + rr) * HH + h0 + cc];
        }
        __syncthreads();
        for (int h = 0; h < 64; ++h)
#pragma unroll
            for (int a = 0; a < 4; ++a) {
                float vv = lv[tk + a][h];
#pragma unroll
                for (int c = 0; c < 4; ++c) acc[a][c] += vv * lo[h][tn + c];
            }
        if (blockIdx.y == 0) {
#pragma unroll
            for (int hh = 0; hh < 16; ++hh) {
                int h = bq_ * 16 + hh;
                bfacc += bv[h0 + h] * lo[h][bn];
            }
        }
        __syncthreads();
    }
    for (int a = 0; a < 4; ++a)
        for (int c = 0; c < 4; ++c)
            WvoT[(size_t)(n0 + tn + c) * DD + k0 + tk + a] = __float2bfloat16(acc[a][c]);
    if (blockIdx.y == 0) {
        lv[bq_][bn] = bfacc;
        __syncthreads();
        if (tid < 64)
            bfinal[n0 + tid] = lv[0][tid] + lv[1][tid] + lv[2][tid] + lv[3][tid] + bo[n0 + tid];
    }
}

// ---------------------------------------------------------------------------
// out[m,n] = Cmat[m,:] @ WvoT[n,:]^T + bfinal[n]  (bf16 MFMA, fp32 output)
__global__ __launch_bounds__(256) void k_out(const __hip_bfloat16* __restrict__ A,
                                             const __hip_bfloat16* __restrict__ Bt,
                                             const float* __restrict__ bfinal,
                                             float* __restrict__ Out) {
    int m0 = blockIdx.x * 64;
    int n0 = blockIdx.y * 256 + (threadIdx.x >> 6) * 64;
    int lane = threadIdx.x & 63;
    int lrow = lane & 15, lk = (lane >> 4) * 8;
    f32x4 acc[4][4] = {};
    const short* Ap = reinterpret_cast<const short*>(A);
    const short* Bp = reinterpret_cast<const short*>(Bt);
    for (int kk = 0; kk < 512; kk += 32) {
        bf16x8 af[4], bfr[4];
#pragma unroll
        for (int i = 0; i < 4; ++i)
            af[i] = *reinterpret_cast<const bf16x8*>(Ap + (size_t)(m0 + i * 16 + lrow) * 512 + kk + lk);
#pragma unroll
        for (int i = 0; i < 4; ++i)
            bfr[i] = *reinterpret_cast<const bf16x8*>(Bp + (size_t)(n0 + i * 16 + lrow) * 512 + kk + lk);
#pragma unroll
        for (int i = 0; i < 4; ++i)
#pragma unroll
            for (int j = 0; j < 4; ++j)
                acc[i][j] = __builtin_amdgcn_mfma_f32_16x16x32_bf16(af[i], bfr[j], acc[i][j], 0, 0, 0);
    }
    int rbase = (lane >> 4) * 4;
    for (int i = 0; i < 4; ++i)
        for (int j = 0; j < 4; ++j) {
            int col = n0 + j * 16 + lrow;
            float bb = bfinal[col];
#pragma unroll
            for (int r = 0; r < 4; ++r) {
                int row = m0 + i * 16 + rbase + r;
                Out[(size_t)row * 512 + col] = acc[i][j][r] + bb;
            }
        }
}

// ---------------------------------------------------------------------------
extern "C" void kernel_launch(void* const* d_in, const int* in_sizes, int n_in,
                              void* d_out, int out_size, void* d_ws, size_t ws_size,
                              hipStream_t stream) {
    const float* query  = (const float*)d_in[0];
    const float* keys   = (const float*)d_in[1];
    const float* values = (const float*)d_in[2];
    const float* Wq = (const float*)d_in[3];
    const float* bq = (const float*)d_in[4];
    const float* Wk = (const float*)d_in[5];
    const float* bk = (const float*)d_in[6];
    const float* Wv = (const float*)d_in[7];
    const float* bv = (const float*)d_in[8];
    const float* Wo = (const float*)d_in[9];
    const float* bo = (const float*)d_in[10];

    float* out  = (float*)d_out;                       // (B,S,D) fp32
    float* attn = out + (size_t)BB * SS * DD;          // (B,S,S) fp32, 268 MB
    __hip_bfloat16* Cmat = (__hip_bfloat16*)attn;      // 16.8 MB scratch inside attn region

    char* ws = (char*)d_ws;                            // ~1 MB total
    __hip_bfloat16* WvoT = (__hip_bfloat16*)(ws);      //   524,288 B
    float* T    = (float*)(ws + 524288);               //   262,144 B
    float* p    = (float*)(ws + 786432);               //    65,536 B
    float* icum = (float*)(ws + 851968);               //    65,536 B
    float* scr  = (float*)(ws + 917504);               //    65,536 B
    float* qv   = (float*)(ws + 983040);               //     8,192 B
    float* wv   = (float*)(ws + 991232);               //     8,192 B
    float* cq   = (float*)(ws + 999424);               //       256 B
    float* bfin = (float*)(ws + 999680);               //     2,048 B

    k_wvo   <<<dim3(8, 8),       256, 0, stream>>>(Wv, Wo, bv, bo, WvoT, bfin);
    k_qproj <<<dim3(8, BB),      256, 0, stream>>>(query, Wq, bq, qv);
    k_w     <<<512,              256, 0, stream>>>(Wk, qv, bk, wv, cq);
    k_scores<<<4096,             256, 0, stream>>>(keys, wv, cq, scr);
    k_softmax<<<BB,             1024, 0, stream>>>(scr, p, icum);
    k_tile  <<<dim3(2, NT, BB),  256, 0, stream>>>(values, p, T);
    k_scan  <<<dim3(2, NT, BB),  256, 0, stream>>>(values, p, icum, T, Cmat);
    k_out   <<<dim3(256, 2),     256, 0, stream>>>(Cmat, WvoT, bfin, out);
    // k_attn LAST: it overwrites the attn region that held Cmat scratch
    k_attn  <<<dim3(SS, BB),     256, 0, stream>>>(p, icum, attn);
}